// Round 4
// baseline (211.359 us; speedup 1.0000x reference)
//
#include <hip/hip_runtime.h>
#include <hip/hip_bf16.h>

#define N_NODES 100000
#define NUM_TYPES 8
#define FACTOR 0.125f  // 1/sqrt(64)

#define S_CHUNK 16128              // nodes per chunk; 16128*4B = 63 KB LDS bins
#define C_CHUNKS 7                 // ceil(100000 / 16128) = 7
#define B_MAX 73                   // segments per chunk -> grid = 7*73 = 511 blocks (~2/CU)

// Pass 1: block -> (c = blockIdx % C, b = blockIdx / C). The 7 chunk-peers of a
// segment are ADJACENT in blockIdx, start together, and walk the identical i
// sequence -> each edge cacheline is fetched from HBM once and served to the
// other 6 peers from L2/L3. 2x software pipeline for memory-level parallelism.
__global__ __launch_bounds__(512) void chunk_sum_kernel(
    const int* __restrict__ centers,
    const int* __restrict__ neighbors,
    const float* __restrict__ eng,
    const int* __restrict__ atom_type,
    const float* __restrict__ scales,
    float* __restrict__ ws,
    int E, int B)
{
    __shared__ float bins[S_CHUNK];
    __shared__ float s_scales[NUM_TYPES * NUM_TYPES];

    const int c = blockIdx.x % C_CHUNKS;   // chunk index (peer-swizzled)
    const int b = blockIdx.x / C_CHUNKS;   // edge-segment index

    if (threadIdx.x < NUM_TYPES * NUM_TYPES) s_scales[threadIdx.x] = scales[threadIdx.x];
    for (int j = threadIdx.x; j < S_CHUNK; j += blockDim.x) bins[j] = 0.0f;
    __syncthreads();

    const int base = c * S_CHUNK;
    const int n4 = E >> 2;
    const int stride = B * blockDim.x;

    const int4*   c4 = (const int4*)centers;
    const int4*   n4p = (const int4*)neighbors;
    const float4* e4 = (const float4*)eng;

    for (int i0 = b * blockDim.x + threadIdx.x; i0 < n4; i0 += 2 * stride) {
        int i1 = i0 + stride;
        bool has1 = i1 < n4;
        int i1c = has1 ? i1 : i0;          // clamped: load is safe, result unused

        // issue all 6 vector loads before any consumption
        int4   cc0 = c4[i0];
        int4   nn0 = n4p[i0];
        float4 e0  = e4[i0];
        int4   cc1 = c4[i1c];
        int4   nn1 = n4p[i1c];
        float4 e1  = e4[i1c];

        {
            unsigned j0 = (unsigned)(cc0.x - base);
            unsigned j1 = (unsigned)(cc0.y - base);
            unsigned j2 = (unsigned)(cc0.z - base);
            unsigned j3 = (unsigned)(cc0.w - base);
            if (j0 < S_CHUNK)
                atomicAdd(&bins[j0], e0.x * s_scales[atom_type[cc0.x] * NUM_TYPES + atom_type[nn0.x]] * FACTOR);
            if (j1 < S_CHUNK)
                atomicAdd(&bins[j1], e0.y * s_scales[atom_type[cc0.y] * NUM_TYPES + atom_type[nn0.y]] * FACTOR);
            if (j2 < S_CHUNK)
                atomicAdd(&bins[j2], e0.z * s_scales[atom_type[cc0.z] * NUM_TYPES + atom_type[nn0.z]] * FACTOR);
            if (j3 < S_CHUNK)
                atomicAdd(&bins[j3], e0.w * s_scales[atom_type[cc0.w] * NUM_TYPES + atom_type[nn0.w]] * FACTOR);
        }
        if (has1) {
            unsigned j0 = (unsigned)(cc1.x - base);
            unsigned j1 = (unsigned)(cc1.y - base);
            unsigned j2 = (unsigned)(cc1.z - base);
            unsigned j3 = (unsigned)(cc1.w - base);
            if (j0 < S_CHUNK)
                atomicAdd(&bins[j0], e1.x * s_scales[atom_type[cc1.x] * NUM_TYPES + atom_type[nn1.x]] * FACTOR);
            if (j1 < S_CHUNK)
                atomicAdd(&bins[j1], e1.y * s_scales[atom_type[cc1.y] * NUM_TYPES + atom_type[nn1.y]] * FACTOR);
            if (j2 < S_CHUNK)
                atomicAdd(&bins[j2], e1.z * s_scales[atom_type[cc1.z] * NUM_TYPES + atom_type[nn1.z]] * FACTOR);
            if (j3 < S_CHUNK)
                atomicAdd(&bins[j3], e1.w * s_scales[atom_type[cc1.w] * NUM_TYPES + atom_type[nn1.w]] * FACTOR);
        }
    }

    // tail (E % 4) — dead for E = 6,400,000
    if (b == 0) {
        for (int i = (n4 << 2) + (int)threadIdx.x; i < E; i += blockDim.x) {
            int cn = centers[i];
            unsigned j = (unsigned)(cn - base);
            if (j < S_CHUNK)
                atomicAdd(&bins[j], eng[i] * s_scales[atom_type[cn] * NUM_TYPES + atom_type[neighbors[i]]] * FACTOR);
        }
    }

    __syncthreads();
    float* dst = ws + ((size_t)c * B + b) * S_CHUNK;
    for (int j = threadIdx.x; j < S_CHUNK; j += blockDim.x) dst[j] = bins[j];
}

// Pass 2: out[n0..n0+3] = sum over B segment-partials. float4-vectorized;
// S_CHUNK and N_NODES are divisible by 4, so a group never straddles a chunk.
__global__ __launch_bounds__(256) void reduce_chunks_kernel(
    const float* __restrict__ ws, float* __restrict__ out, int B)
{
    int t = blockIdx.x * blockDim.x + threadIdx.x;
    int n0 = t << 2;
    if (n0 >= N_NODES) return;
    int c = n0 / S_CHUNK;
    int j = n0 - c * S_CHUNK;
    const float* p = ws + (size_t)c * B * S_CHUNK + j;
    float4 s = make_float4(0.f, 0.f, 0.f, 0.f);
    for (int b = 0; b < B; ++b) {
        float4 v = *(const float4*)(p + (size_t)b * S_CHUNK);
        s.x += v.x; s.y += v.y; s.z += v.z; s.w += v.w;
    }
    *(float4*)(out + n0) = s;
}

// Fallback (tiny workspace only): direct atomic scatter into out.
__global__ __launch_bounds__(256) void edge_sum_atomic_kernel(
    const int* __restrict__ centers, const int* __restrict__ neighbors,
    const float* __restrict__ eng, const int* __restrict__ atom_type,
    const float* __restrict__ scales, float* __restrict__ out, int E)
{
    __shared__ float s_scales[NUM_TYPES * NUM_TYPES];
    if (threadIdx.x < NUM_TYPES * NUM_TYPES) s_scales[threadIdx.x] = scales[threadIdx.x];
    __syncthreads();
    int tid = blockIdx.x * blockDim.x + threadIdx.x;
    int stride = gridDim.x * blockDim.x;
    for (int i = tid; i < E; i += stride) {
        int cn = centers[i];
        float v = eng[i] * s_scales[atom_type[cn] * NUM_TYPES + atom_type[neighbors[i]]] * FACTOR;
        unsafeAtomicAdd(&out[cn], v);
    }
}

extern "C" void kernel_launch(void* const* d_in, const int* in_sizes, int n_in,
                              void* d_out, int out_size, void* d_ws, size_t ws_size,
                              hipStream_t stream) {
    const int E = in_sizes[1];  // edge_eng element count
    const int* edge_index = (const int*)d_in[0];   // [2, E]
    const float* edge_eng = (const float*)d_in[1]; // [E, 1]
    const int* atom_type = (const int*)d_in[2];    // [N, 1]
    const float* scales = (const float*)d_in[3];   // [T, T]
    float* out = (float*)d_out;

    const int* centers = edge_index;
    const int* neighbors = edge_index + E;

    size_t per_b = (size_t)C_CHUNKS * S_CHUNK * sizeof(float);
    int B = (int)(ws_size / per_b);
    if (B > B_MAX) B = B_MAX;

    if (B >= 1) {
        float* ws = (float*)d_ws;
        chunk_sum_kernel<<<C_CHUNKS * B, 512, 0, stream>>>(
            centers, neighbors, edge_eng, atom_type, scales, ws, E, B);
        reduce_chunks_kernel<<<(N_NODES / 4 + 255) / 256, 256, 0, stream>>>(ws, out, B);
    } else {
        hipMemsetAsync(d_out, 0, (size_t)out_size * sizeof(float), stream);
        edge_sum_atomic_kernel<<<1024, 256, 0, stream>>>(
            centers, neighbors, edge_eng, atom_type, scales, out, E);
    }
}